// Round 17
// baseline (284.533 us; speedup 1.0000x reference)
//
#include <hip/hip_runtime.h>
#include <math.h>

#define J   29
#define CH  3
#define JC  87            // J*CH
#define E0  56
#define B   256
#define T   1024
#define FRAMES (B*T)      // 262144
#define FPC 64            // frames per chunk (= lanes)
#define CPB 4             // chunks per block
#define NBLK (FRAMES/(FPC*CPB)) // 1024
#define CHUNK_F4 1392     // float4s per chunk (22272 B)
#define BPB (T/(FPC*CPB)) // 4 partials per batch
#define SLOTS 4           // padded nnz per row (overflow beyond)
#define PROWS 32          // padded row count
#define MAXOV 96          // overflow capacity
#define WAVES 8
#define RPW 4             // rows per wave

// ---- prep: identical to R14/R16 (proven) ------------------------------------
__global__ void prep_kernel(const int* __restrict__ ei,
                            int2* __restrict__ pairs,
                            int*  __restrict__ ov_rp,
                            int2* __restrict__ ov_pairs)
{
    __shared__ float M[J * J];
    __shared__ float dinv[J];
    __shared__ int   cnt_ov[J];
    int tid = threadIdx.x;

    for (int i = tid; i < J * J; i += 64) M[i] = 0.f;
    if (tid < J) {
        int d = 1;
        for (int e = 0; e < E0; ++e) d += (ei[E0 + e] == tid) ? 1 : 0;
        dinv[tid] = rsqrtf((float)d);
    }
    __syncthreads();

    if (tid < J) {
        for (int e = 0; e < E0; ++e) {
            if (ei[E0 + e] == tid) {
                int s = ei[e];
                M[tid * J + s] += dinv[s] * dinv[tid];
            }
        }
        M[tid * J + tid] += dinv[tid] * dinv[tid];
        int c = 0;
        for (int i = 0; i < J; ++i) c += (M[tid * J + i] != 0.f) ? 1 : 0;
        cnt_ov[tid] = (c > SLOTS) ? (c - SLOTS) : 0;
    }
    __syncthreads();

    if (tid == 0) {
        int a = 0;
        for (int j = 0; j < J; ++j) { ov_rp[j] = a; a += cnt_ov[j]; }
        for (int j = J; j <= 32; ++j) ov_rp[j] = a;
    }
    __syncthreads();

    if (tid < PROWS) {
        int2 zero; zero.x = 0; zero.y = 0;
        if (tid < J) {
            int s = 0, p = ov_rp[tid];
            for (int i = 0; i < J; ++i) {
                float v = M[tid * J + i];
                if (v != 0.f) {
                    if (s < SLOTS) {
                        int2 pr; pr.x = i * 12; pr.y = __float_as_int(v);
                        pairs[tid * SLOTS + s] = pr;
                    } else {
                        int2 pr; pr.x = (tid << 16) | (i * 12); pr.y = __float_as_int(v);
                        ov_pairs[p++] = pr;
                    }
                    ++s;
                }
            }
            for (; s < SLOTS; ++s) pairs[tid * SLOTS + s] = zero;
        } else {
            for (int s = 0; s < SLOTS; ++s) pairs[tid * SLOTS + s] = zero;
        }
    }
    __syncthreads();
    if (tid == 0) {
        int a = ov_rp[J];
        for (int i = a; i < MAXOV; ++i) { int2 pr; pr.x = 0; pr.y = 0; ov_pairs[i] = pr; }
    }
}

// ---- shared body: V0 full (real), V1 stage-only, V2 compute-only -----------
// Probes remap blockIdx so a G-times-larger grid re-processes the input G times.
template<int V>
__device__ __forceinline__ void gcn_body(const float* __restrict__ x,
                                         const float* __restrict__ Wp,
                                         const float* __restrict__ bp,
                                         const int2* __restrict__ pairs,
                                         const int*  __restrict__ ov_rp,
                                         const int2* __restrict__ ov_pairs,
                                         float* __restrict__ partials) {
    __shared__ float4 xs4[CHUNK_F4];
    __shared__ int2   s_ov[MAXOV];

    int tid  = threadIdx.x;
    int lane = tid & 63;
    int wv   = tid >> 6;
    int rowbase = __builtin_amdgcn_readfirstlane(wv * RPW);
    int bid = (V == 0) ? blockIdx.x : (blockIdx.x & (NBLK - 1));

    float sW[9], sb[CH];
#pragma unroll
    for (int i = 0; i < 9; ++i) sW[i] = Wp[i];
#pragma unroll
    for (int i = 0; i < CH; ++i) sb[i] = bp[i];
    int ov0 = ov_rp[rowbase], ov1 = ov_rp[rowbase + RPW];
    if (tid < MAXOV) s_ov[tid] = ov_pairs[tid];

    const float4* src4 = (const float4*)x + (size_t)bid * (CPB * CHUNK_F4);
    int i2 = 1024 + tid; if (i2 > CHUNK_F4 - 1) i2 = CHUNK_F4 - 1;

    float4 pf0 = src4[tid];
    float4 pf1 = src4[512 + tid];
    float4 pf2 = src4[i2];

    float acc[RPW][CH];
#pragma unroll
    for (int r = 0; r < RPW; ++r)
#pragma unroll
        for (int c = 0; c < CH; ++c) acc[r][c] = 0.f;
    float keep = 0.f;

#pragma unroll
    for (int c = 0; c < CPB; ++c) {
        __syncthreads();
        xs4[tid]       = pf0;
        xs4[512 + tid] = pf1;
        xs4[i2]        = pf2;
        __syncthreads();

        if (V != 2) {
            if (c + 1 < CPB) {
                const float4* s2 = src4 + (c + 1) * CHUNK_F4;
                pf0 = s2[tid];
                pf1 = s2[512 + tid];
                pf2 = s2[i2];
            }
        }

        if (V == 0 || V == 2) {
            const char* xf = (const char*)xs4 + lane * 348;
            float y[RPW][CH];
#pragma unroll
            for (int R = 0; R < RPW; ++R) {
                float a0 = 0.f, a1 = 0.f, a2 = 0.f;
#pragma unroll
                for (int sl = 0; sl < SLOTS; ++sl) {
                    int2 pr = pairs[(rowbase + R) * SLOTS + sl];  // uniform s_load
                    float v = __int_as_float(pr.y);
                    const float* q = (const float*)(xf + pr.x);
                    a0 += v * q[0];
                    a1 += v * q[1];
                    a2 += v * q[2];
                }
                y[R][0] = a0; y[R][1] = a1; y[R][2] = a2;
            }
            for (int e = ov0; e < ov1; ++e) {
                int2 pr = s_ov[e];
                int row = pr.x >> 16;
                int off = pr.x & 0xFFFF;
                float v = __int_as_float(pr.y);
                const float* q = (const float*)(xf + off);
                float d0 = v * q[0], d1 = v * q[1], d2 = v * q[2];
#pragma unroll
                for (int R = 0; R < RPW; ++R)
                    if (row == rowbase + R) { y[R][0] += d0; y[R][1] += d1; y[R][2] += d2; }
            }
#pragma unroll
            for (int R = 0; R < RPW; ++R)
#pragma unroll
                for (int ch = 0; ch < CH; ++ch) {
                    float t = y[R][0] * sW[0 * CH + ch]
                            + y[R][1] * sW[1 * CH + ch]
                            + y[R][2] * sW[2 * CH + ch]
                            + sb[ch];
                    acc[R][ch] += fmaxf(t, 0.f);
                }
        } else {
            keep += ((const float*)xs4)[tid];   // keep stage live
        }
    }
    if (V == 1) acc[0][0] += keep;

    __syncthreads();
    float* red = (float*)xs4;
#pragma unroll
    for (int R = 0; R < RPW; ++R) {
        int j = rowbase + R;
        if (j < J) {
#pragma unroll
            for (int ch = 0; ch < CH; ++ch)
                red[lane * JC + j * CH + ch] = acc[R][ch];
        }
    }
    __syncthreads();
    if (tid < JC) {
        float a = 0.f;
#pragma unroll
        for (int L = 0; L < FPC; ++L) a += red[L * JC + tid];
        partials[(size_t)bid * JC + tid] = a;
    }
}

__global__ __launch_bounds__(512, 2)
void gcn_v0_full(const float* __restrict__ x, const float* __restrict__ Wp,
                 const float* __restrict__ bp, const int2* __restrict__ pairs,
                 const int* __restrict__ ov_rp, const int2* __restrict__ ov_pairs,
                 float* __restrict__ partials)
{ gcn_body<0>(x, Wp, bp, pairs, ov_rp, ov_pairs, partials); }

__global__ __launch_bounds__(512, 2)
void gcn_v1_stage(const float* __restrict__ x, const float* __restrict__ Wp,
                  const float* __restrict__ bp, const int2* __restrict__ pairs,
                  const int* __restrict__ ov_rp, const int2* __restrict__ ov_pairs,
                  float* __restrict__ partials)
{ gcn_body<1>(x, Wp, bp, pairs, ov_rp, ov_pairs, partials); }

__global__ __launch_bounds__(512, 2)
void gcn_v2_compute(const float* __restrict__ x, const float* __restrict__ Wp,
                    const float* __restrict__ bp, const int2* __restrict__ pairs,
                    const int* __restrict__ ov_rp, const int2* __restrict__ ov_pairs,
                    float* __restrict__ partials)
{ gcn_body<2>(x, Wp, bp, pairs, ov_rp, ov_pairs, partials); }

// ---- V4 probe: 4-wave blocks (256 thr), 8 rows/wave, same pipeline ---------
__global__ __launch_bounds__(256, 4)
void gcn_v4_small(const float* __restrict__ x, const float* __restrict__ Wp,
                  const float* __restrict__ bp, const int2* __restrict__ pairs,
                  const int* __restrict__ ov_rp, const int2* __restrict__ ov_pairs,
                  float* __restrict__ partials) {
    __shared__ float4 xs4[CHUNK_F4];
    __shared__ int2   s_ov[MAXOV];

    int tid  = threadIdx.x;
    int lane = tid & 63;
    int wv   = tid >> 6;                                  // 0..3
    int rowbase = __builtin_amdgcn_readfirstlane(wv * 8); // 0,8,16,24

    float sW[9], sb[CH];
#pragma unroll
    for (int i = 0; i < 9; ++i) sW[i] = Wp[i];
#pragma unroll
    for (int i = 0; i < CH; ++i) sb[i] = bp[i];
    int ov0 = ov_rp[rowbase], ov1 = ov_rp[rowbase + 8];
    if (tid < MAXOV) s_ov[tid] = ov_pairs[tid];

    int bid = blockIdx.x & (NBLK - 1);
    const float4* src4 = (const float4*)x + (size_t)bid * (CPB * CHUNK_F4);
    int i5 = 1280 + tid; if (i5 > CHUNK_F4 - 1) i5 = CHUNK_F4 - 1;

    float4 p0 = src4[tid],        p1 = src4[256 + tid], p2 = src4[512 + tid];
    float4 p3 = src4[768 + tid],  p4 = src4[1024 + tid], p5 = src4[i5];

    float acc[8][CH];
#pragma unroll
    for (int r = 0; r < 8; ++r)
#pragma unroll
        for (int c = 0; c < CH; ++c) acc[r][c] = 0.f;

#pragma unroll
    for (int c = 0; c < CPB; ++c) {
        __syncthreads();
        xs4[tid] = p0; xs4[256 + tid] = p1; xs4[512 + tid] = p2;
        xs4[768 + tid] = p3; xs4[1024 + tid] = p4; xs4[i5] = p5;
        __syncthreads();
        if (c + 1 < CPB) {
            const float4* s2 = src4 + (c + 1) * CHUNK_F4;
            p0 = s2[tid]; p1 = s2[256 + tid]; p2 = s2[512 + tid];
            p3 = s2[768 + tid]; p4 = s2[1024 + tid]; p5 = s2[i5];
        }
        const char* xf = (const char*)xs4 + lane * 348;
        float y[8][CH];
#pragma unroll
        for (int R = 0; R < 8; ++R) {
            float a0 = 0.f, a1 = 0.f, a2 = 0.f;
#pragma unroll
            for (int sl = 0; sl < SLOTS; ++sl) {
                int2 pr = pairs[(rowbase + R) * SLOTS + sl];
                float v = __int_as_float(pr.y);
                const float* q = (const float*)(xf + pr.x);
                a0 += v * q[0]; a1 += v * q[1]; a2 += v * q[2];
            }
            y[R][0] = a0; y[R][1] = a1; y[R][2] = a2;
        }
        for (int e = ov0; e < ov1; ++e) {
            int2 pr = s_ov[e];
            int row = pr.x >> 16;
            int off = pr.x & 0xFFFF;
            float v = __int_as_float(pr.y);
            const float* q = (const float*)(xf + off);
            float d0 = v * q[0], d1 = v * q[1], d2 = v * q[2];
#pragma unroll
            for (int R = 0; R < 8; ++R)
                if (row == rowbase + R) { y[R][0] += d0; y[R][1] += d1; y[R][2] += d2; }
        }
#pragma unroll
        for (int R = 0; R < 8; ++R)
#pragma unroll
            for (int ch = 0; ch < CH; ++ch) {
                float t = y[R][0] * sW[0 * CH + ch]
                        + y[R][1] * sW[1 * CH + ch]
                        + y[R][2] * sW[2 * CH + ch]
                        + sb[ch];
                acc[R][ch] += fmaxf(t, 0.f);
            }
    }

    __syncthreads();
    float* red = (float*)xs4;
#pragma unroll
    for (int R = 0; R < 8; ++R) {
        int j = rowbase + R;
        if (j < J) {
#pragma unroll
            for (int ch = 0; ch < CH; ++ch)
                red[lane * JC + j * CH + ch] = acc[R][ch];
        }
    }
    __syncthreads();
    if (tid < JC) {
        float a = 0.f;
#pragma unroll
        for (int L = 0; L < FPC; ++L) a += red[L * JC + tid];
        partials[(size_t)bid * JC + tid] = a;
    }
}

// ---- finalize: identical to R14 ---------------------------------------------
__global__ void finalize_kernel(const float* __restrict__ partials,
                                const float* __restrict__ fcW,
                                const float* __restrict__ fcb,
                                float* __restrict__ out) {
    __shared__ float h[JC];
    int b = blockIdx.x, tid = threadIdx.x;
    if (tid < JC) {
        float a = 0.f;
#pragma unroll
        for (int p = 0; p < BPB; ++p)
            a += partials[(size_t)(b * BPB + p) * JC + tid];
        a *= (1.0f / (float)T);
        h[tid] = a;
        out[(size_t)b * JC + tid] = a;
    }
    __syncthreads();
    if (tid < 2) {
        float a = fcb[tid];
        for (int r = 0; r < JC; ++r) a += h[r] * fcW[r * 2 + tid];
        out[(size_t)B * JC + b * 2 + tid] = 1.0f / (1.0f + expf(-a));
    }
}

extern "C" void kernel_launch(void* const* d_in, const int* in_sizes, int n_in,
                              void* d_out, int out_size, void* d_ws, size_t ws_size,
                              hipStream_t stream) {
    const float* x   = (const float*)d_in[0];
    const int*   ei  = (const int*)d_in[1];
    const float* W   = (const float*)d_in[4];
    const float* bb  = (const float*)d_in[5];
    const float* fcW = (const float*)d_in[6];
    const float* fcb = (const float*)d_in[7];

    char* ws = (char*)d_ws;
    int2* pairs    = (int2*)ws;
    int2* ov_pairs = pairs + PROWS * SLOTS;
    int*  ov_rp    = (int*)(ov_pairs + MAXOV);
    float* partials  = (float*)(ws + 4096);         // V0 (real) partials
    float* probe_v1  = (float*)(ws + (4u << 20));
    float* probe_v2  = (float*)(ws + (8u << 20));
    float* probe_v4  = (float*)(ws + (12u << 20));

    prep_kernel<<<1, 64, 0, stream>>>(ei, pairs, ov_rp, ov_pairs);
    // V0 first (cold, R14 conditions). Probes after, grid-multiplied so their
    // dispatch times exceed the ~52us harness fills and appear in top-5.
    gcn_v0_full   <<<NBLK,     512, 0, stream>>>(x, W, bb, pairs, ov_rp, ov_pairs, partials);
    gcn_v1_stage  <<<NBLK * 8, 512, 0, stream>>>(x, W, bb, pairs, ov_rp, ov_pairs, probe_v1);
    gcn_v2_compute<<<NBLK * 8, 512, 0, stream>>>(x, W, bb, pairs, ov_rp, ov_pairs, probe_v2);
    gcn_v4_small  <<<NBLK * 4, 256, 0, stream>>>(x, W, bb, pairs, ov_rp, ov_pairs, probe_v4);
    finalize_kernel<<<B, 128, 0, stream>>>(partials, fcW, fcb, (float*)d_out);
}

// Round 18
// 39.169 us; speedup vs baseline: 7.2642x; 7.2642x over previous
//
#include <hip/hip_runtime.h>
#include <math.h>

#define J   29
#define CH  3
#define JC  87            // J*CH
#define E0  56
#define B   256
#define T   1024
#define FRAMES (B*T)      // 262144
#define FPC 64            // frames per chunk (= lanes)
#define CPB 4             // chunks per block (even!)
#define NBLK (FRAMES/(FPC*CPB)) // 1024
#define CHUNK_F4 1392     // float4s per chunk (22272 B)
#define BPB (T/(FPC*CPB)) // 4 partials per batch
#define SLOTS 4           // padded nnz per row (overflow beyond)
#define PROWS 32          // padded row count
#define MAXOV 96          // overflow capacity
#define WAVES 8
#define RPW 4             // rows per wave

// ---- prep: identical to R14 (proven) ----------------------------------------
__global__ void prep_kernel(const int* __restrict__ ei,
                            int2* __restrict__ pairs,
                            int*  __restrict__ ov_rp,
                            int2* __restrict__ ov_pairs)
{
    __shared__ float M[J * J];
    __shared__ float dinv[J];
    __shared__ int   cnt_ov[J];
    int tid = threadIdx.x;

    for (int i = tid; i < J * J; i += 64) M[i] = 0.f;
    if (tid < J) {
        int d = 1;
        for (int e = 0; e < E0; ++e) d += (ei[E0 + e] == tid) ? 1 : 0;
        dinv[tid] = rsqrtf((float)d);
    }
    __syncthreads();

    if (tid < J) {
        for (int e = 0; e < E0; ++e) {
            if (ei[E0 + e] == tid) {
                int s = ei[e];
                M[tid * J + s] += dinv[s] * dinv[tid];
            }
        }
        M[tid * J + tid] += dinv[tid] * dinv[tid];
        int c = 0;
        for (int i = 0; i < J; ++i) c += (M[tid * J + i] != 0.f) ? 1 : 0;
        cnt_ov[tid] = (c > SLOTS) ? (c - SLOTS) : 0;
    }
    __syncthreads();

    if (tid == 0) {
        int a = 0;
        for (int j = 0; j < J; ++j) { ov_rp[j] = a; a += cnt_ov[j]; }
        for (int j = J; j <= 32; ++j) ov_rp[j] = a;
    }
    __syncthreads();

    if (tid < PROWS) {
        int2 zero; zero.x = 0; zero.y = 0;
        if (tid < J) {
            int s = 0, p = ov_rp[tid];
            for (int i = 0; i < J; ++i) {
                float v = M[tid * J + i];
                if (v != 0.f) {
                    if (s < SLOTS) {
                        int2 pr; pr.x = i * 12; pr.y = __float_as_int(v);
                        pairs[tid * SLOTS + s] = pr;
                    } else {
                        int2 pr; pr.x = (tid << 16) | (i * 12); pr.y = __float_as_int(v);
                        ov_pairs[p++] = pr;
                    }
                    ++s;
                }
            }
            for (; s < SLOTS; ++s) pairs[tid * SLOTS + s] = zero;
        } else {
            for (int s = 0; s < SLOTS; ++s) pairs[tid * SLOTS + s] = zero;
        }
    }
    __syncthreads();
    if (tid == 0) {
        int a = ov_rp[J];
        for (int i = a; i < MAXOV; ++i) { int2 pr; pr.x = 0; pr.y = 0; ov_pairs[i] = pr; }
    }
}

// ---- main: LDS double-buffer, 1 barrier/chunk, named prefetch regs ----------
__global__ __launch_bounds__(512, 2)
void gcn_main(const float* __restrict__ x,
              const float* __restrict__ Wp,
              const float* __restrict__ bp,
              const int2* __restrict__ pairs,
              const int*  __restrict__ ov_rp,
              const int2* __restrict__ ov_pairs,
              float* __restrict__ partials) {
    __shared__ float4 xs4[2][CHUNK_F4];   // 2 x 22272 B
    __shared__ int2   s_ov[MAXOV];

    int tid  = threadIdx.x;
    int lane = tid & 63;
    int wv   = tid >> 6;
    int rowbase = __builtin_amdgcn_readfirstlane(wv * RPW);

    float sW[9], sb[CH];
#pragma unroll
    for (int i = 0; i < 9; ++i) sW[i] = Wp[i];
#pragma unroll
    for (int i = 0; i < CH; ++i) sb[i] = bp[i];
    int ov0 = ov_rp[rowbase], ov1 = ov_rp[rowbase + RPW];
    if (tid < MAXOV) s_ov[tid] = ov_pairs[tid];

    const float4* src4 = (const float4*)x + (size_t)blockIdx.x * (CPB * CHUNK_F4);
    int i2 = 1024 + tid; if (i2 > CHUNK_F4 - 1) i2 = CHUNK_F4 - 1;

    // prologue: chunk 0 -> regs -> buf0; chunk 1 issued before first barrier
    float4 pfA0 = src4[tid], pfA1 = src4[512 + tid], pfA2 = src4[i2];
    xs4[0][tid] = pfA0; xs4[0][512 + tid] = pfA1; xs4[0][i2] = pfA2;
    const float4* s1 = src4 + CHUNK_F4;
    float4 pfB0 = s1[tid], pfB1 = s1[512 + tid], pfB2 = s1[i2];

    float acc[RPW][CH];
#pragma unroll
    for (int r = 0; r < RPW; ++r)
#pragma unroll
        for (int c = 0; c < CH; ++c) acc[r][c] = 0.f;

    __syncthreads();   // buf0 + s_ov visible

#define COMPUTE_CHUNK(BUF)                                                    \
    {                                                                         \
        const char* xf = (const char*)xs4[BUF] + lane * 348;                  \
        float y[RPW][CH];                                                     \
        _Pragma("unroll")                                                     \
        for (int R = 0; R < RPW; ++R) {                                       \
            float a0 = 0.f, a1 = 0.f, a2 = 0.f;                               \
            _Pragma("unroll")                                                 \
            for (int sl = 0; sl < SLOTS; ++sl) {                              \
                int2 pr = pairs[(rowbase + R) * SLOTS + sl];                  \
                float v = __int_as_float(pr.y);                               \
                const float* q = (const float*)(xf + pr.x);                   \
                a0 += v * q[0]; a1 += v * q[1]; a2 += v * q[2];               \
            }                                                                 \
            y[R][0] = a0; y[R][1] = a1; y[R][2] = a2;                         \
        }                                                                     \
        for (int e = ov0; e < ov1; ++e) {                                     \
            int2 pr = s_ov[e];                                                \
            int row = pr.x >> 16; int off = pr.x & 0xFFFF;                    \
            float v = __int_as_float(pr.y);                                   \
            const float* q = (const float*)(xf + off);                        \
            float d0 = v * q[0], d1 = v * q[1], d2 = v * q[2];                \
            _Pragma("unroll")                                                 \
            for (int R = 0; R < RPW; ++R)                                     \
                if (row == rowbase + R) { y[R][0] += d0; y[R][1] += d1; y[R][2] += d2; } \
        }                                                                     \
        _Pragma("unroll")                                                     \
        for (int R = 0; R < RPW; ++R)                                         \
            _Pragma("unroll")                                                 \
            for (int ch = 0; ch < CH; ++ch) {                                 \
                float t = y[R][0] * sW[0 * CH + ch]                           \
                        + y[R][1] * sW[1 * CH + ch]                           \
                        + y[R][2] * sW[2 * CH + ch]                           \
                        + sb[ch];                                             \
                acc[R][ch] += fmaxf(t, 0.f);                                  \
            }                                                                 \
    }

#pragma unroll
    for (int c = 0; c < CPB; c += 2) {
        // ---- even chunk c from buf0; chunk c+1 (pfB) in flight ----
        COMPUTE_CHUNK(0);
        xs4[1][tid] = pfB0; xs4[1][512 + tid] = pfB1; xs4[1][i2] = pfB2;
        if (c + 2 < CPB) {                 // issue chunk c+2
            const float4* sn = src4 + (c + 2) * CHUNK_F4;
            pfA0 = sn[tid]; pfA1 = sn[512 + tid]; pfA2 = sn[i2];
        }
        __syncthreads();                   // buf1 (chunk c+1) visible

        // ---- odd chunk c+1 from buf1; chunk c+2 (pfA) in flight ----
        COMPUTE_CHUNK(1);
        if (c + 2 < CPB) {
            // every wave finished COMPUTE(buf0) before the barrier above
            xs4[0][tid] = pfA0; xs4[0][512 + tid] = pfA1; xs4[0][i2] = pfA2;
            if (c + 3 < CPB) {             // issue chunk c+3
                const float4* sn = src4 + (c + 3) * CHUNK_F4;
                pfB0 = sn[tid]; pfB1 = sn[512 + tid]; pfB2 = sn[i2];
            }
            __syncthreads();               // buf0 (chunk c+2) visible
        }
    }

    // ---- epilogue: transposed LDS write + 87-thread column reduce ----------
    __syncthreads();
    float* red = (float*)xs4[0];
#pragma unroll
    for (int R = 0; R < RPW; ++R) {
        int j = rowbase + R;
        if (j < J) {
#pragma unroll
            for (int ch = 0; ch < CH; ++ch)
                red[lane * JC + j * CH + ch] = acc[R][ch];
        }
    }
    __syncthreads();
    if (tid < JC) {
        float a = 0.f;
#pragma unroll
        for (int L = 0; L < FPC; ++L) a += red[L * JC + tid];
        partials[(size_t)blockIdx.x * JC + tid] = a;
    }
}

// ---- finalize: identical to R14 ---------------------------------------------
__global__ void finalize_kernel(const float* __restrict__ partials,
                                const float* __restrict__ fcW,
                                const float* __restrict__ fcb,
                                float* __restrict__ out) {
    __shared__ float h[JC];
    int b = blockIdx.x, tid = threadIdx.x;
    if (tid < JC) {
        float a = 0.f;
#pragma unroll
        for (int p = 0; p < BPB; ++p)
            a += partials[(size_t)(b * BPB + p) * JC + tid];
        a *= (1.0f / (float)T);
        h[tid] = a;
        out[(size_t)b * JC + tid] = a;
    }
    __syncthreads();
    if (tid < 2) {
        float a = fcb[tid];
        for (int r = 0; r < JC; ++r) a += h[r] * fcW[r * 2 + tid];
        out[(size_t)B * JC + b * 2 + tid] = 1.0f / (1.0f + expf(-a));
    }
}

extern "C" void kernel_launch(void* const* d_in, const int* in_sizes, int n_in,
                              void* d_out, int out_size, void* d_ws, size_t ws_size,
                              hipStream_t stream) {
    const float* x   = (const float*)d_in[0];
    const int*   ei  = (const int*)d_in[1];
    const float* W   = (const float*)d_in[4];
    const float* bb  = (const float*)d_in[5];
    const float* fcW = (const float*)d_in[6];
    const float* fcb = (const float*)d_in[7];

    char* ws = (char*)d_ws;
    int2* pairs    = (int2*)ws;
    int2* ov_pairs = pairs + PROWS * SLOTS;
    int*  ov_rp    = (int*)(ov_pairs + MAXOV);
    float* partials = (float*)(ws + 4096);            // 1024*87 floats

    prep_kernel<<<1, 64, 0, stream>>>(ei, pairs, ov_rp, ov_pairs);
    gcn_main<<<NBLK, WAVES * 64, 0, stream>>>(x, W, bb, pairs, ov_rp, ov_pairs, partials);
    finalize_kernel<<<B, 128, 0, stream>>>(partials, fcW, fcb, (float*)d_out);
}